// Round 11
// baseline (22896.497 us; speedup 1.0000x reference)
//
#include <hip/hip_runtime.h>
#include <math.h>

#define B 256
#define T 256
#define U 512
#define L 256
#define V 64
#define G4U 2048
#define BU (B * U)
#define HBUF 262144   // ushorts per (layer,buf) interleaved h panel: 256 rows * 1024

typedef __attribute__((ext_vector_type(8))) short bf16x8;
typedef __attribute__((ext_vector_type(16))) float f32x16;

__device__ __forceinline__ unsigned short bf16_hi(float x) {
    union { float f; unsigned int u; } c; c.f = x;
    unsigned int r = c.u + 0x7fffu + ((c.u >> 16) & 1u);   // RNE
    return (unsigned short)(r >> 16);
}
__device__ __forceinline__ float bf16_f(unsigned short h) {
    union { unsigned int u; float f; } c; c.u = ((unsigned int)h) << 16;
    return c.f;
}

// ---- point-to-point role-group flag sync --------------------------------
// flag[bid] at bar[bid*16] (own 64B line). Monotonic: 1 = init; p+2 = phase p
// done. Consumers poll one flag per lane (wave 0), then per-flag acquire.
__device__ __forceinline__ void flags_wait(int* bar, int wmask, int target, int lane)
{
    if (threadIdx.x < 64) {
        #pragma unroll
        for (int r = 0; r < 4; ++r) {
            if (wmask & (1 << r)) {
                const int fi = (r * 64 + lane) * 16;
                while (__hip_atomic_load(&bar[fi], __ATOMIC_RELAXED,
                                         __HIP_MEMORY_SCOPE_AGENT) < target)
                    __builtin_amdgcn_s_sleep(1);
                (void)__hip_atomic_load(&bar[fi], __ATOMIC_ACQUIRE,
                                        __HIP_MEMORY_SCOPE_AGENT);
            }
        }
    }
    __syncthreads();
}
__device__ __forceinline__ void flags_pub(int* bar, int bid, int val)
{
    asm volatile("s_waitcnt vmcnt(0)" ::: "memory");   // each wave's stores done
    __syncthreads();
    if (threadIdx.x == 0)
        __hip_atomic_store(&bar[bid * 16], val, __ATOMIC_RELEASE,
                           __HIP_MEMORY_SCOPE_AGENT);
}

// Simple 4-chunk GEMM (role0 x-part): 8 A-loads then 12 MFMAs. B from LDS.
__device__ __forceinline__ void gemm4(const unsigned short* __restrict__ abase,
                                      const unsigned short* bhiB,
                                      const unsigned short* bloB,
                                      int kh8, f32x16& acc)
{
    bf16x8 ah[4], al[4];
    #pragma unroll
    for (int i = 0; i < 4; ++i) {
        ah[i] = *(const bf16x8*)(abase + i * 32 + kh8);
        al[i] = *(const bf16x8*)(abase + i * 32 + 16 + kh8);
    }
    #pragma unroll
    for (int i = 0; i < 4; ++i) {
        bf16x8 bh = *(const bf16x8*)(bhiB + i * 512);
        bf16x8 bl = *(const bf16x8*)(bloB + i * 512);
        acc = __builtin_amdgcn_mfma_f32_32x32x16_bf16(ah[i], bh, acc, 0, 0, 0);
        acc = __builtin_amdgcn_mfma_f32_32x32x16_bf16(ah[i], bl, acc, 0, 0, 0);
        acc = __builtin_amdgcn_mfma_f32_32x32x16_bf16(al[i], bh, acc, 0, 0, 0);
    }
}

// Software-pipelined GEMM over NCH 16-k chunks, batch=8 (16 A-loads in flight).
template<int NCH>
__device__ __forceinline__ void gemm_sub(const unsigned short* __restrict__ abase,
                                         const unsigned short* bhiB,
                                         const unsigned short* bloB,
                                         int kh8, f32x16& acc)
{
    constexpr int NB = NCH / 8;
    bf16x8 ah[2][8], al[2][8];
    #pragma unroll
    for (int i = 0; i < 8; ++i) {
        ah[0][i] = *(const bf16x8*)(abase + i * 32 + kh8);
        al[0][i] = *(const bf16x8*)(abase + i * 32 + 16 + kh8);
    }
    #pragma unroll
    for (int b = 0; b < NB; ++b) {
        const int cur = b & 1, nxt = cur ^ 1;
        if (b + 1 < NB) {
            #pragma unroll
            for (int i = 0; i < 8; ++i) {
                const int c = (b + 1) * 8 + i;
                ah[nxt][i] = *(const bf16x8*)(abase + c * 32 + kh8);
                al[nxt][i] = *(const bf16x8*)(abase + c * 32 + 16 + kh8);
            }
        }
        #pragma unroll
        for (int i = 0; i < 8; ++i) {
            const int c = b * 8 + i;
            bf16x8 bh = *(const bf16x8*)(bhiB + c * 512);
            bf16x8 bl = *(const bf16x8*)(bloB + c * 512);
            acc = __builtin_amdgcn_mfma_f32_32x32x16_bf16(ah[cur][i], bh, acc, 0, 0, 0);
            acc = __builtin_amdgcn_mfma_f32_32x32x16_bf16(ah[cur][i], bl, acc, 0, 0, 0);
            acc = __builtin_amdgcn_mfma_f32_32x32x16_bf16(al[cur][i], bh, acc, 0, 0, 0);
        }
    }
}

// Fused 3-layer LSTM stack, diagonal-pipelined, split-bf16 MFMA.
// Blocks 0-63: layer0; 64-127: layer1; 128-191: layer2; 192-255: projection
// (decoder only; encoder launches 192 blocks).
// LDS 128KB: both weight planes resident. h exchanged through LLC via regular
// (cacheable) stores — NT only for `out` (never re-read). R10's NT h-stores
// pushed h to HBM (6.6 MB/phase refetch), the measured 46µs/phase wall.
__global__ void __launch_bounds__(512, 1)
vae_stack(const unsigned short* __restrict__ xI,
          const float* __restrict__ Wx0, const float* __restrict__ Wh0,
          const float* __restrict__ Wx1, const float* __restrict__ Wh1,
          const float* __restrict__ Wx2, const float* __restrict__ Wh2,
          const float* __restrict__ cb_base, const float* __restrict__ rb0,
          unsigned short* __restrict__ h,
          const float* __restrict__ projW, const float* __restrict__ projB,
          float* __restrict__ out, int nphase, int* __restrict__ bar)
{
    __shared__ __align__(16) char smem[131072];
    const int nb = gridDim.x;
    const int tid = threadIdx.x;
    const int bid = blockIdx.x;
    const int role = bid >> 6;
    const int ug = bid & 63;
    const int lane = tid & 63;
    const int wv = tid >> 6;        // wave id
    const int m0 = wv * 32;

    // role dependence masks: {r-1 producer, r own-prev, r+1 WAR}
    const int allmask = (nb == 256) ? 0b1111 : 0b0111;
    int wmask;
    if      (role == 0) wmask = 0b0011;
    else if (role == 1) wmask = 0b0111;
    else if (role == 2) wmask = (nb == 256) ? 0b1110 : 0b0110;
    else                wmask = 0b0100;

    // zero all h buffers (6 interleaved panels = 786432 uints), grid-stride,
    // cacheable stores (zeros become LLC-resident)
    {
        unsigned int* hz = (unsigned int*)h;
        const int stride = nb * 512;
        for (int i = bid * 512 + tid; i < 786432; i += stride)
            hz[i] = 0u;
    }

    auto HP = [&](int layer, int buf) -> unsigned short* {
        return h + (size_t)(layer * 2 + buf) * HBUF;
    };

    if (role < 3) {
        const int K  = (role == 0) ? 576 : 1024;
        const int Dx = (role == 0) ? 64 : 512;
        unsigned short* Whi = (unsigned short*)smem;             // lower 64KB
        unsigned short* Wlo = (unsigned short*)(smem + 65536);   // upper 64KB

        // one-time weight stage, both planes (col slot n = u*4+g; col = g*512+ug*8+u)
        const float* WxL = (role == 0) ? Wx0 : ((role == 1) ? Wx1 : Wx2);
        const float* WhL = (role == 0) ? Wh0 : ((role == 1) ? Wh1 : Wh2);
        for (int idx = tid; idx < K * 32; idx += 512) {
            int k = idx >> 5, n = idx & 31, u = n >> 2, g = n & 3;
            int col = g * 512 + ug * 8 + u;
            float w = (k < Dx) ? WxL[(size_t)k * G4U + col]
                               : WhL[(size_t)(k - Dx) * G4U + col];
            unsigned short hi = bf16_hi(w);
            int off = ((k >> 3) * 32 + n) * 8 + (k & 7);
            Whi[off] = hi;
            Wlo[off] = bf16_hi(w - bf16_f(hi));
        }

        const bool userb = (role == 0) && (rb0 != nullptr);
        const float colbias = userb ? 0.0f
                            : cb_base[role * 2048 + ug * 32 + (lane & 31)];
        float cst[16];
        #pragma unroll
        for (int i = 0; i < 16; ++i) cst[i] = 0.0f;

        const int arow = m0 + (lane & 31);      // A row (batch)
        const int kh8  = (lane >> 5) * 8;       // k-half offset in 16-chunk
        const int frg  = (lane >> 5) * 256 + (lane & 31) * 8;  // B frag offset

        // init rendezvous: ALL blocks zeroed h slices -> full-grid wait once
        flags_pub(bar, bid, 1);
        flags_wait(bar, allmask, 1, lane);

        for (int p = 0; p < nphase; ++p) {
            flags_wait(bar, wmask, p + 1, lane);   // deps finished phase p-1
            const int t = p - role;
            if (t >= 0 && t < T) {
                const int wr = t & 1, rd = wr ^ 1;
                f32x16 acc;
                #pragma unroll
                for (int i = 0; i < 16; ++i) acc[i] = 0.0f;

                if (role == 0) {
                    gemm4(xI + ((size_t)arow * T + t) * 128,
                          Whi + frg, Wlo + frg, kh8, acc);
                    gemm_sub<32>(HP(0, rd) + (size_t)arow * 1024,
                                 Whi + 4 * 512 + frg, Wlo + 4 * 512 + frg, kh8, acc);
                } else {
                    gemm_sub<32>(HP(role - 1, wr) + (size_t)arow * 1024,
                                 Whi + frg, Wlo + frg, kh8, acc);
                    gemm_sub<32>(HP(role, rd) + (size_t)arow * 1024,
                                 Whi + 32 * 512 + frg, Wlo + 32 * 512 + frg, kh8, acc);
                }

                // pointwise: C layout col=lane&31, row=(r&3)+8*(r>>2)+4*(lane>>5)
                const int n = lane & 31, g = n & 3, u8 = n >> 2, hi5 = lane >> 5;
                unsigned short* hw = HP(role, wr);
                const int gu = ug * 8 + u8;
                const int guo = (gu >> 4) * 32 + (gu & 15);   // interleaved offset
                const bool g1 = (g & 1), g2 = (g & 2);
                #pragma unroll
                for (int r = 0; r < 16; ++r) {
                    int grow = m0 + (r & 3) + 8 * (r >> 2) + 4 * hi5;
                    float z = acc[r] + colbias;
                    if (userb) z += rb0[(size_t)grow * G4U + ug * 32 + n];
                    float zb = __shfl_xor(z, 1, 64);
                    float zc = __shfl_xor(z, 2, 64);
                    float zd = __shfl_xor(z, 3, 64);
                    float t01 = g1 ? zb : z,  t23 = g1 ? zd : zc;
                    float u01 = g1 ? z  : zb, u23 = g1 ? zc : zd;
                    float zi = g2 ? t23 : t01;
                    float zf = g2 ? u23 : u01;
                    float zG = g2 ? t01 : t23;
                    float zo = g2 ? u01 : u23;
                    float ig = 1.0f / (1.0f + expf(-zi));
                    float fg = 1.0f / (1.0f + expf(-zf));
                    float gg = tanhf(zG);
                    float og = 1.0f / (1.0f + expf(-zo));
                    cst[r] = fg * cst[r] + ig * gg;
                    float hv = og * tanhf(cst[r]);
                    if (g == 0) {
                        unsigned short hh2 = bf16_hi(hv);
                        unsigned short hl2 = bf16_hi(hv - bf16_f(hh2));
                        size_t ho = (size_t)grow * 1024 + guo;
                        hw[ho] = hh2;          // cacheable: h stays LLC-resident
                        hw[ho + 16] = hl2;
                    }
                }
            }
            flags_pub(bar, bid, p + 2);
        }
    } else {
        // ---------------- projection + argmax (decoder only) ----------------
        float* hrow  = (float*)smem;            // [4][512]
        float* parts = (float*)(smem + 8192);   // [256]
        const int b0p = ug * 4;
        const float pbv = projW ? projB[lane] : 0.0f;
        const int r = wv & 3, kp = wv >> 2, v = lane;
        flags_pub(bar, bid, 1);
        flags_wait(bar, allmask, 1, lane);
        for (int p = 0; p < nphase; ++p) {
            flags_wait(bar, wmask, p + 1, lane);
            const int tp = p - 3;
            if (projW && tp >= 0 && tp < T) {
                {   // stage 4 h2 rows (hi+lo recon) into LDS
                    int rr = tid >> 7, kq = (tid & 127) * 4;   // 4 units, same chunk
                    const unsigned short* hb2 = HP(2, tp & 1)
                        + (size_t)(b0p + rr) * 1024 + (kq >> 4) * 32 + (kq & 15);
                    ushort4 vh = *(const ushort4*)hb2;
                    ushort4 vl = *(const ushort4*)(hb2 + 16);
                    float4 f;
                    f.x = bf16_f(vh.x) + bf16_f(vl.x);
                    f.y = bf16_f(vh.y) + bf16_f(vl.y);
                    f.z = bf16_f(vh.z) + bf16_f(vl.z);
                    f.w = bf16_f(vh.w) + bf16_f(vl.w);
                    *(float4*)(hrow + rr * 512 + kq) = f;
                }
                __syncthreads();
                // wave w: r=w&3 (batch row), kp=w>>2 (k half); lane = vocab v.
                float acc = 0.0f;
                const float* wp = projW + (size_t)v * 512 + kp * 256;
                const float* hp = hrow + r * 512 + kp * 256;
                #pragma unroll 8
                for (int q = 0; q < 64; ++q) {
                    float4 w  = *(const float4*)(wp + q * 4);
                    float4 hq = *(const float4*)(hp + q * 4);
                    acc = fmaf(w.x, hq.x, acc); acc = fmaf(w.y, hq.y, acc);
                    acc = fmaf(w.z, hq.z, acc); acc = fmaf(w.w, hq.w, acc);
                }
                if (kp == 1) parts[r * 64 + v] = acc;
                __syncthreads();
                if (kp == 0) {
                    float logit = acc + parts[r * 64 + v] + pbv;
                    int grow = b0p + r;
                    __builtin_nontemporal_store(
                        logit, &out[(size_t)B * T + ((size_t)grow * T + tp) * V + v]);
                    float best = logit; int bi = v;
                    #pragma unroll
                    for (int off = 32; off; off >>= 1) {
                        float ov = __shfl_xor(best, off, 64);
                        int oi  = __shfl_xor(bi, off, 64);
                        if (ov > best || (ov == best && oi < bi)) { best = ov; bi = oi; }
                    }
                    if (v == 0)
                        __builtin_nontemporal_store((float)bi,
                                                    &out[(size_t)grow * T + tp]);
                }
            }
            flags_pub(bar, bid, p + 2);
        }
    }
}

// ---------------- prep kernels ----------------
// x interleaved: xI[pos*128 + c*32 + kk] = hi(emb[k=c*16+kk]), +16 = lo
__global__ void embed_split_k(const int* __restrict__ tok, const float* __restrict__ emb,
                              unsigned short* __restrict__ xI)
{
    int idx = blockIdx.x * 256 + threadIdx.x;   // B*T*16 quads
    int pos = idx >> 4, q = idx & 15;
    int c = q >> 2, kk4 = (q & 3) * 4;          // k = q*4 = c*16 + kk4
    int tk = tok[pos];
    float4 v = *(const float4*)(emb + (size_t)tk * V + q * 4);
    ushort4 hh, ll;
    hh.x = bf16_hi(v.x); ll.x = bf16_hi(v.x - bf16_f(hh.x));
    hh.y = bf16_hi(v.y); ll.y = bf16_hi(v.y - bf16_f(hh.y));
    hh.z = bf16_hi(v.z); ll.z = bf16_hi(v.z - bf16_f(hh.z));
    hh.w = bf16_hi(v.w); ll.w = bf16_hi(v.w - bf16_f(hh.w));
    size_t base = (size_t)pos * 128 + c * 32 + kk4;
    *(ushort4*)(xI + base) = hh;
    *(ushort4*)(xI + base + 16) = ll;
}

__global__ void latent_k(const unsigned short* __restrict__ h2,
                         const float* __restrict__ eps,
                         const float* __restrict__ wm, const float* __restrict__ bm,
                         const float* __restrict__ wsig, const float* __restrict__ bs,
                         float* __restrict__ lat)
{
    __shared__ float hr[U];
    int b = blockIdx.x, l = threadIdx.x;
    {
        size_t o1 = (size_t)b * 1024 + (l >> 4) * 32 + (l & 15);
        int l2 = l + 256;
        size_t o2 = (size_t)b * 1024 + (l2 >> 4) * 32 + (l2 & 15);
        hr[l]  = bf16_f(h2[o1]) + bf16_f(h2[o1 + 16]);
        hr[l2] = bf16_f(h2[o2]) + bf16_f(h2[o2 + 16]);
    }
    __syncthreads();
    float am = bm[l], as = bs[l];
    for (int k = 0; k < U; ++k) {
        float h = hr[k];
        am = fmaf(h, wm[(size_t)k * L + l], am);
        as = fmaf(h, wsig[(size_t)k * L + l], as);
    }
    lat[(size_t)b * L + l] = am + expf(as * 0.5f) * eps[(size_t)b * L + l];
}

// xcr[b][ugi*32+u*4+g] = dec_b0 + latent @ dec_Wx0[0:L]  (col oc = g*512+ugi*8+u)
__global__ void xcr_k(const float* __restrict__ lat, const float* __restrict__ Wx0,
                      const float* __restrict__ b0v, float* __restrict__ xcr)
{
    __shared__ float lr[L];
    int b = blockIdx.x >> 3;
    int oc = (blockIdx.x & 7) * 256 + threadIdx.x;
    lr[threadIdx.x] = lat[(size_t)b * L + threadIdx.x];
    __syncthreads();
    float acc = b0v[oc];
    for (int k = 0; k < L; ++k) acc = fmaf(lr[k], Wx0[(size_t)k * G4U + oc], acc);
    int g = oc >> 9, rest = oc & 511, ugi = rest >> 3, u = rest & 7;
    xcr[(size_t)b * G4U + ugi * 32 + u * 4 + g] = acc;
}

__global__ void biasref_k(const float* s0, const float* s1, const float* s2,
                          const float* s3, const float* s4, float* __restrict__ ebr)
{
    int idx = blockIdx.x * 256 + threadIdx.x;   // 5*2048
    int which = idx >> 11, oc = idx & 2047;
    const float* s = which == 0 ? s0 : which == 1 ? s1 : which == 2 ? s2
                   : which == 3 ? s3 : s4;
    int g = oc >> 9, rest = oc & 511, ugi = rest >> 3, u = rest & 7;
    ebr[which * 2048 + ugi * 32 + u * 4 + g] = s[oc];
}

// Wt[v][k] = dec_W[k][v]  (transposed projection weight, float4-loadable rows)
__global__ void wtprep_k(const float* __restrict__ W, float* __restrict__ Wt)
{
    int idx = blockIdx.x * 256 + threadIdx.x;   // 32768
    int k = idx >> 6, v = idx & 63;
    Wt[(size_t)v * 512 + k] = W[idx];
}

__global__ void barinit_k(int* __restrict__ bar)
{
    bar[blockIdx.x * 256 + threadIdx.x] = 0;   // 4096 ints (256 flag lines)
}

__global__ void sentinel_k(float* __restrict__ out, float val) { out[threadIdx.x] = val; }

extern "C" void kernel_launch(void* const* d_in, const int* in_sizes, int n_in,
                              void* d_out, int out_size, void* d_ws, size_t ws_size,
                              hipStream_t stream)
{
    const int*   tokens   = (const int*)  d_in[0];
    const float* eps      = (const float*)d_in[1];
    const float* emb      = (const float*)d_in[2];
    const float* enc_Wx0  = (const float*)d_in[3];
    const float* enc_Wh0  = (const float*)d_in[4];
    const float* enc_b0   = (const float*)d_in[5];
    const float* enc_Wx12 = (const float*)d_in[6];
    const float* enc_Wh12 = (const float*)d_in[7];
    const float* enc_b12  = (const float*)d_in[8];
    const float* w_mean   = (const float*)d_in[9];
    const float* b_mean   = (const float*)d_in[10];
    const float* w_sigma  = (const float*)d_in[11];
    const float* b_sigma  = (const float*)d_in[12];
    const float* dec_Wx0  = (const float*)d_in[13];
    const float* dec_Wh0  = (const float*)d_in[14];
    const float* dec_b0   = (const float*)d_in[15];
    const float* dec_Wx12 = (const float*)d_in[16];
    const float* dec_Wh12 = (const float*)d_in[17];
    const float* dec_b12  = (const float*)d_in[18];
    const float* dec_W    = (const float*)d_in[19];
    const float* dec_b    = (const float*)d_in[20];
    float* out = (float*)d_out;

    // workspace carve-up (all 16B aligned)
    unsigned short* xI  = (unsigned short*)d_ws;                  // B*T*128 us
    unsigned short* h   = xI + (size_t)B * T * 128;               // 6*HBUF us
    float* lat = (float*)(h + 6 * (size_t)HBUF);                  // B*L
    float* xcr = lat + (size_t)B * L;                             // B*2048
    float* ebr = xcr + (size_t)B * G4U;                           // 5*2048
    float* Wt  = ebr + 5 * G4U;                                   // 64*512
    int*   bar = (int*)(Wt + 64 * 512);                           // 4096 ints
    size_t need = (size_t)((char*)(bar + 4096) - (char*)d_ws);
    if (ws_size < need) {
        sentinel_k<<<dim3(1), dim3(64), 0, stream>>>(out, -1.0e6f);
        return;
    }

    const size_t UG = (size_t)U * G4U;

    embed_split_k<<<dim3(B * T * 16 / 256), dim3(256), 0, stream>>>(tokens, emb, xI);
    biasref_k<<<dim3(40), dim3(256), 0, stream>>>(enc_b0, enc_b12, enc_b12 + G4U,
                                                  dec_b12, dec_b12 + G4U, ebr);
    wtprep_k<<<dim3(128), dim3(256), 0, stream>>>(dec_W, Wt);

    auto coop = [&](int grid, const float* Wx0_, const float* Wh0_,
                    const float* Wx1_, const float* Wh1_,
                    const float* Wx2_, const float* Wh2_,
                    const float* cbb, const float* rb,
                    const float* pW, const float* pB, int np) -> hipError_t {
        const unsigned short* a_xI = xI;
        unsigned short* a_h = h;
        float* a_out = out;
        int* a_bar = bar;
        void* args[] = { (void*)&a_xI,
                         (void*)&Wx0_, (void*)&Wh0_, (void*)&Wx1_, (void*)&Wh1_,
                         (void*)&Wx2_, (void*)&Wh2_,
                         (void*)&cbb, (void*)&rb, (void*)&a_h,
                         (void*)&pW, (void*)&pB, (void*)&a_out, (void*)&np,
                         (void*)&a_bar };
        return hipLaunchCooperativeKernel((void*)vae_stack, dim3(grid), dim3(512),
                                          args, 0, stream);
    };

    // ---------------- encoder (192 blocks: no projection role) --------------
    barinit_k<<<dim3(16), dim3(256), 0, stream>>>(bar);
    hipError_t e1 = coop(192, enc_Wx0, enc_Wh0, enc_Wx12, enc_Wh12,
                         enc_Wx12 + UG, enc_Wh12 + UG,
                         ebr, nullptr, nullptr, nullptr, T + 2);

    // latent head reads encoder h2[t=255] (buf 1): interleaved panel 5
    latent_k<<<dim3(B), dim3(256), 0, stream>>>(h + 5 * (size_t)HBUF,
                                                eps, w_mean, b_mean, w_sigma, b_sigma, lat);
    xcr_k<<<dim3(2048), dim3(256), 0, stream>>>(lat, dec_Wx0, dec_b0, xcr);

    // ---------------- decoder (256 blocks, fused projection) ----------------
    barinit_k<<<dim3(16), dim3(256), 0, stream>>>(bar);
    hipError_t e2 = coop(256, dec_Wx0 + (size_t)L * G4U, dec_Wh0, dec_Wx12, dec_Wh12,
                         dec_Wx12 + UG, dec_Wh12 + UG,
                         ebr + 2 * G4U, xcr, Wt, dec_b, T + 3);

    if (e1 != hipSuccess || e2 != hipSuccess) {
        sentinel_k<<<dim3(1), dim3(64), 0, stream>>>(out, -3.0e6f);
    }
}

// Round 12
// 22067.372 us; speedup vs baseline: 1.0376x; 1.0376x over previous
//
#include <hip/hip_runtime.h>
#include <math.h>

#define B 256
#define T 256
#define U 512
#define L 256
#define V 64
#define G4U 2048
#define BU (B * U)
#define HBUF 262144   // ushorts per (layer,buf) interleaved h panel: 256 rows * 1024

typedef __attribute__((ext_vector_type(8))) short bf16x8;
typedef __attribute__((ext_vector_type(16))) float f32x16;

__device__ __forceinline__ unsigned short bf16_hi(float x) {
    union { float f; unsigned int u; } c; c.f = x;
    unsigned int r = c.u + 0x7fffu + ((c.u >> 16) & 1u);   // RNE
    return (unsigned short)(r >> 16);
}
__device__ __forceinline__ float bf16_f(unsigned short h) {
    union { unsigned int u; float f; } c; c.u = ((unsigned int)h) << 16;
    return c.f;
}

// ---- MALL-coherent (sc0 sc1) access helpers -----------------------------
// Bypass the per-XCD L2 => no buffer_wbl2/buffer_inv needed anywhere.
// Loads are issued WITHOUT waitcnt; callers must execute coh_drain() before
// consuming results (rule: sched_barrier stops MFMA hoisting past waitcnt).
__device__ __forceinline__ void ld_coh16(const void* p, bf16x8& d) {
    asm volatile("global_load_dwordx4 %0, %1, off sc0 sc1"
                 : "=v"(d) : "v"(p));
}
__device__ __forceinline__ void ld_coh8(const void* p, unsigned long long& d) {
    asm volatile("global_load_dwordx2 %0, %1, off sc0 sc1"
                 : "=v"(d) : "v"(p));
}
__device__ __forceinline__ void st_coh32(void* p, unsigned int v) {
    asm volatile("global_store_dword %0, %1, off sc0 sc1"
                 :: "v"(p), "v"(v) : "memory");
}
__device__ __forceinline__ unsigned int ld_coh32_wait(const void* p) {
    unsigned int r;
    asm volatile("global_load_dword %0, %1, off sc0 sc1\n\t"
                 "s_waitcnt vmcnt(0)"
                 : "=v"(r) : "v"(p) : "memory");
    return r;
}
__device__ __forceinline__ void coh_drain() {
    asm volatile("s_waitcnt vmcnt(0)" ::: "memory");
    __builtin_amdgcn_sched_barrier(0);
}

// ---- point-to-point role-group flag sync (relaxed, coherent, no fences) --
// flag[bid] at bar[bid*16] (own 64B line). Monotonic: 1 = init; p+2 = phase p
// done. Producer: vmcnt(0)-drain of coherent stores -> sc1 flag store.
// Consumer: sc1 poll; data reads are sc1 too, so no invalidate needed.
__device__ __forceinline__ void flags_wait(int* bar, int wmask, int target, int lane)
{
    if (threadIdx.x < 64) {
        #pragma unroll
        for (int r = 0; r < 4; ++r) {
            if (wmask & (1 << r)) {
                const int fi = (r * 64 + lane) * 16;
                while ((int)ld_coh32_wait(&bar[fi]) < target)
                    __builtin_amdgcn_s_sleep(1);
            }
        }
    }
    __syncthreads();
}
__device__ __forceinline__ void flags_pub(int* bar, int bid, int val)
{
    asm volatile("s_waitcnt vmcnt(0)" ::: "memory");   // all stores MALL-acked
    __syncthreads();
    if (threadIdx.x == 0)
        st_coh32(&bar[bid * 16], (unsigned int)val);
}

// Simple 4-chunk GEMM (role0 x-part): xI is read-only -> normal cached loads.
__device__ __forceinline__ void gemm4(const unsigned short* __restrict__ abase,
                                      const unsigned short* bhiB,
                                      const unsigned short* bloB,
                                      int kh8, f32x16& acc)
{
    bf16x8 ah[4], al[4];
    #pragma unroll
    for (int i = 0; i < 4; ++i) {
        ah[i] = *(const bf16x8*)(abase + i * 32 + kh8);
        al[i] = *(const bf16x8*)(abase + i * 32 + 16 + kh8);
    }
    #pragma unroll
    for (int i = 0; i < 4; ++i) {
        bf16x8 bh = *(const bf16x8*)(bhiB + i * 512);
        bf16x8 bl = *(const bf16x8*)(bloB + i * 512);
        acc = __builtin_amdgcn_mfma_f32_32x32x16_bf16(ah[i], bh, acc, 0, 0, 0);
        acc = __builtin_amdgcn_mfma_f32_32x32x16_bf16(ah[i], bl, acc, 0, 0, 0);
        acc = __builtin_amdgcn_mfma_f32_32x32x16_bf16(al[i], bh, acc, 0, 0, 0);
    }
}

// Pipelined GEMM over NCH 16-k chunks of a COHERENT (sc1) A panel, batch=8.
// Batch b+1's 16 loads issue before batch b's 24 MFMAs; coh_drain per batch.
template<int NCH>
__device__ __forceinline__ void gemm_sub_coh(const unsigned short* abase,
                                             const unsigned short* bhiB,
                                             const unsigned short* bloB,
                                             int kh8, f32x16& acc)
{
    constexpr int NB = NCH / 8;
    bf16x8 ah[2][8], al[2][8];
    #pragma unroll
    for (int i = 0; i < 8; ++i) {
        ld_coh16(abase + i * 32 + kh8,      ah[0][i]);
        ld_coh16(abase + i * 32 + 16 + kh8, al[0][i]);
    }
    coh_drain();
    #pragma unroll
    for (int b = 0; b < NB; ++b) {
        const int cur = b & 1, nxt = cur ^ 1;
        if (b + 1 < NB) {
            #pragma unroll
            for (int i = 0; i < 8; ++i) {
                const int c = (b + 1) * 8 + i;
                ld_coh16(abase + c * 32 + kh8,      ah[nxt][i]);
                ld_coh16(abase + c * 32 + 16 + kh8, al[nxt][i]);
            }
        }
        #pragma unroll
        for (int i = 0; i < 8; ++i) {
            const int c = b * 8 + i;
            bf16x8 bh = *(const bf16x8*)(bhiB + c * 512);
            bf16x8 bl = *(const bf16x8*)(bloB + c * 512);
            acc = __builtin_amdgcn_mfma_f32_32x32x16_bf16(ah[cur][i], bh, acc, 0, 0, 0);
            acc = __builtin_amdgcn_mfma_f32_32x32x16_bf16(ah[cur][i], bl, acc, 0, 0, 0);
            acc = __builtin_amdgcn_mfma_f32_32x32x16_bf16(al[cur][i], bh, acc, 0, 0, 0);
        }
        coh_drain();   // batch b+1 loads complete; also final no-op drain
    }
}

// Fused 3-layer LSTM stack, diagonal-pipelined, split-bf16 MFMA.
// Blocks 0-63: layer0; 64-127: layer1; 128-191: layer2; 192-255: projection
// (decoder only; encoder launches 192 blocks).
// LDS 128KB: both weight planes resident. h exchanged via MALL-coherent
// sc0 sc1 accesses + relaxed flags — ZERO per-phase L2 writeback/invalidate
// (the measured flat ~40µs/phase wall of R8-R11).
__global__ void __launch_bounds__(512, 1)
vae_stack(const unsigned short* __restrict__ xI,
          const float* __restrict__ Wx0, const float* __restrict__ Wh0,
          const float* __restrict__ Wx1, const float* __restrict__ Wh1,
          const float* __restrict__ Wx2, const float* __restrict__ Wh2,
          const float* __restrict__ cb_base, const float* __restrict__ rb0,
          unsigned short* __restrict__ h,
          const float* __restrict__ projW, const float* __restrict__ projB,
          float* __restrict__ out, int nphase, int* __restrict__ bar)
{
    __shared__ __align__(16) char smem[131072];
    const int nb = gridDim.x;
    const int tid = threadIdx.x;
    const int bid = blockIdx.x;
    const int role = bid >> 6;
    const int ug = bid & 63;
    const int lane = tid & 63;
    const int wv = tid >> 6;        // wave id
    const int m0 = wv * 32;

    // role dependence masks: {r-1 producer, r own-prev, r+1 WAR}
    const int allmask = (nb == 256) ? 0b1111 : 0b0111;
    int wmask;
    if      (role == 0) wmask = 0b0011;
    else if (role == 1) wmask = 0b0111;
    else if (role == 2) wmask = (nb == 256) ? 0b1110 : 0b0110;
    else                wmask = 0b0100;

    // zero all h buffers COHERENTLY (consumers read via sc1 -> MALL)
    {
        unsigned int* hz = (unsigned int*)h;
        const int stride = nb * 512;
        for (int i = bid * 512 + tid; i < 786432; i += stride)
            st_coh32(hz + i, 0u);
    }

    auto HP = [&](int layer, int buf) -> unsigned short* {
        return h + (size_t)(layer * 2 + buf) * HBUF;
    };

    if (role < 3) {
        const int K  = (role == 0) ? 576 : 1024;
        const int Dx = (role == 0) ? 64 : 512;
        unsigned short* Whi = (unsigned short*)smem;             // lower 64KB
        unsigned short* Wlo = (unsigned short*)(smem + 65536);   // upper 64KB

        // one-time weight stage, both planes (col slot n = u*4+g; col = g*512+ug*8+u)
        const float* WxL = (role == 0) ? Wx0 : ((role == 1) ? Wx1 : Wx2);
        const float* WhL = (role == 0) ? Wh0 : ((role == 1) ? Wh1 : Wh2);
        for (int idx = tid; idx < K * 32; idx += 512) {
            int k = idx >> 5, n = idx & 31, u = n >> 2, g = n & 3;
            int col = g * 512 + ug * 8 + u;
            float w = (k < Dx) ? WxL[(size_t)k * G4U + col]
                               : WhL[(size_t)(k - Dx) * G4U + col];
            unsigned short hi = bf16_hi(w);
            int off = ((k >> 3) * 32 + n) * 8 + (k & 7);
            Whi[off] = hi;
            Wlo[off] = bf16_hi(w - bf16_f(hi));
        }

        const bool userb = (role == 0) && (rb0 != nullptr);
        const float colbias = userb ? 0.0f
                            : cb_base[role * 2048 + ug * 32 + (lane & 31)];
        float cst[16];
        #pragma unroll
        for (int i = 0; i < 16; ++i) cst[i] = 0.0f;

        const int arow = m0 + (lane & 31);      // A row (batch)
        const int kh8  = (lane >> 5) * 8;       // k-half offset in 16-chunk
        const int frg  = (lane >> 5) * 256 + (lane & 31) * 8;  // B frag offset

        // init rendezvous: ALL blocks' coherent zeros visible
        flags_pub(bar, bid, 1);
        flags_wait(bar, allmask, 1, lane);

        for (int p = 0; p < nphase; ++p) {
            flags_wait(bar, wmask, p + 1, lane);   // deps finished phase p-1
            const int t = p - role;
            if (t >= 0 && t < T) {
                const int wr = t & 1, rd = wr ^ 1;
                f32x16 acc;
                #pragma unroll
                for (int i = 0; i < 16; ++i) acc[i] = 0.0f;

                if (role == 0) {
                    gemm4(xI + ((size_t)arow * T + t) * 128,
                          Whi + frg, Wlo + frg, kh8, acc);
                    gemm_sub_coh<32>(HP(0, rd) + (size_t)arow * 1024,
                                     Whi + 4 * 512 + frg, Wlo + 4 * 512 + frg, kh8, acc);
                } else {
                    gemm_sub_coh<32>(HP(role - 1, wr) + (size_t)arow * 1024,
                                     Whi + frg, Wlo + frg, kh8, acc);
                    gemm_sub_coh<32>(HP(role, rd) + (size_t)arow * 1024,
                                     Whi + 32 * 512 + frg, Wlo + 32 * 512 + frg, kh8, acc);
                }

                // pointwise: C layout col=lane&31, row=(r&3)+8*(r>>2)+4*(lane>>5)
                const int n = lane & 31, g = n & 3, u8 = n >> 2, hi5 = lane >> 5;
                unsigned short* hw = HP(role, wr);
                const int gu = ug * 8 + u8;
                const int guo = (gu >> 4) * 32 + (gu & 15);   // interleaved offset
                const bool g1 = (g & 1), g2 = (g & 2);
                const bool store_t = (g == 0) && !(u8 & 1);   // u32 pair stores
                #pragma unroll
                for (int r = 0; r < 16; ++r) {
                    int grow = m0 + (r & 3) + 8 * (r >> 2) + 4 * hi5;
                    float z = acc[r] + colbias;
                    if (userb) z += rb0[(size_t)grow * G4U + ug * 32 + n];
                    float zb = __shfl_xor(z, 1, 64);
                    float zc = __shfl_xor(z, 2, 64);
                    float zd = __shfl_xor(z, 3, 64);
                    float t01 = g1 ? zb : z,  t23 = g1 ? zd : zc;
                    float u01 = g1 ? z  : zb, u23 = g1 ? zc : zd;
                    float zi = g2 ? t23 : t01;
                    float zf = g2 ? u23 : u01;
                    float zG = g2 ? t01 : t23;
                    float zo = g2 ? u01 : u23;
                    float ig = 1.0f / (1.0f + expf(-zi));
                    float fg = 1.0f / (1.0f + expf(-zf));
                    float gg = tanhf(zG);
                    float og = 1.0f / (1.0f + expf(-zo));
                    cst[r] = fg * cst[r] + ig * gg;
                    float hv = og * tanhf(cst[r]);
                    unsigned short hh2 = bf16_hi(hv);
                    unsigned short hl2 = bf16_hi(hv - bf16_f(hh2));
                    // pair with partner unit (u8^1) via lane^4
                    unsigned int hh_p = (unsigned int)__shfl_xor((int)hh2, 4, 64);
                    unsigned int hl_p = (unsigned int)__shfl_xor((int)hl2, 4, 64);
                    if (store_t) {
                        size_t ho = (size_t)grow * 1024 + guo;
                        st_coh32(hw + ho,      (unsigned int)hh2 | (hh_p << 16));
                        st_coh32(hw + ho + 16, (unsigned int)hl2 | (hl_p << 16));
                    }
                }
            }
            flags_pub(bar, bid, p + 2);
        }
    } else {
        // ---------------- projection + argmax (decoder only) ----------------
        float* hrow  = (float*)smem;            // [4][512]
        float* parts = (float*)(smem + 8192);   // [256]
        const int b0p = ug * 4;
        const float pbv = projW ? projB[lane] : 0.0f;
        const int r = wv & 3, kp = wv >> 2, v = lane;
        flags_pub(bar, bid, 1);
        flags_wait(bar, allmask, 1, lane);
        for (int p = 0; p < nphase; ++p) {
            flags_wait(bar, wmask, p + 1, lane);
            const int tp = p - 3;
            if (projW && tp >= 0 && tp < T) {
                {   // stage 4 h2 rows (hi+lo recon) into LDS — coherent reads
                    int rr = tid >> 7, kq = (tid & 127) * 4;   // 4 units, same chunk
                    const unsigned short* hb2 = HP(2, tp & 1)
                        + (size_t)(b0p + rr) * 1024 + (kq >> 4) * 32 + (kq & 15);
                    unsigned long long uh, ul;
                    ld_coh8(hb2, uh);
                    ld_coh8(hb2 + 16, ul);
                    coh_drain();
                    float4 f;
                    f.x = bf16_f((unsigned short)(uh))       + bf16_f((unsigned short)(ul));
                    f.y = bf16_f((unsigned short)(uh >> 16)) + bf16_f((unsigned short)(ul >> 16));
                    f.z = bf16_f((unsigned short)(uh >> 32)) + bf16_f((unsigned short)(ul >> 32));
                    f.w = bf16_f((unsigned short)(uh >> 48)) + bf16_f((unsigned short)(ul >> 48));
                    *(float4*)(hrow + rr * 512 + kq) = f;
                }
                __syncthreads();
                // wave w: r=w&3 (batch row), kp=w>>2 (k half); lane = vocab v.
                float acc = 0.0f;
                const float* wp = projW + (size_t)v * 512 + kp * 256;
                const float* hp = hrow + r * 512 + kp * 256;
                #pragma unroll 8
                for (int q = 0; q < 64; ++q) {
                    float4 w  = *(const float4*)(wp + q * 4);
                    float4 hq = *(const float4*)(hp + q * 4);
                    acc = fmaf(w.x, hq.x, acc); acc = fmaf(w.y, hq.y, acc);
                    acc = fmaf(w.z, hq.z, acc); acc = fmaf(w.w, hq.w, acc);
                }
                if (kp == 1) parts[r * 64 + v] = acc;
                __syncthreads();
                if (kp == 0) {
                    float logit = acc + parts[r * 64 + v] + pbv;
                    int grow = b0p + r;
                    __builtin_nontemporal_store(
                        logit, &out[(size_t)B * T + ((size_t)grow * T + tp) * V + v]);
                    float best = logit; int bi = v;
                    #pragma unroll
                    for (int off = 32; off; off >>= 1) {
                        float ov = __shfl_xor(best, off, 64);
                        int oi  = __shfl_xor(bi, off, 64);
                        if (ov > best || (ov == best && oi < bi)) { best = ov; bi = oi; }
                    }
                    if (v == 0)
                        __builtin_nontemporal_store((float)bi,
                                                    &out[(size_t)grow * T + tp]);
                }
            }
            flags_pub(bar, bid, p + 2);
        }
    }
}

// ---------------- prep kernels ----------------
// x interleaved: xI[pos*128 + c*32 + kk] = hi(emb[k=c*16+kk]), +16 = lo
__global__ void embed_split_k(const int* __restrict__ tok, const float* __restrict__ emb,
                              unsigned short* __restrict__ xI)
{
    int idx = blockIdx.x * 256 + threadIdx.x;   // B*T*16 quads
    int pos = idx >> 4, q = idx & 15;
    int c = q >> 2, kk4 = (q & 3) * 4;          // k = q*4 = c*16 + kk4
    int tk = tok[pos];
    float4 v = *(const float4*)(emb + (size_t)tk * V + q * 4);
    ushort4 hh, ll;
    hh.x = bf16_hi(v.x); ll.x = bf16_hi(v.x - bf16_f(hh.x));
    hh.y = bf16_hi(v.y); ll.y = bf16_hi(v.y - bf16_f(hh.y));
    hh.z = bf16_hi(v.z); ll.z = bf16_hi(v.z - bf16_f(hh.z));
    hh.w = bf16_hi(v.w); ll.w = bf16_hi(v.w - bf16_f(hh.w));
    size_t base = (size_t)pos * 128 + c * 32 + kk4;
    *(ushort4*)(xI + base) = hh;
    *(ushort4*)(xI + base + 16) = ll;
}

__global__ void latent_k(const unsigned short* __restrict__ h2,
                         const float* __restrict__ eps,
                         const float* __restrict__ wm, const float* __restrict__ bm,
                         const float* __restrict__ wsig, const float* __restrict__ bs,
                         float* __restrict__ lat)
{
    __shared__ float hr[U];
    int b = blockIdx.x, l = threadIdx.x;
    {
        size_t o1 = (size_t)b * 1024 + (l >> 4) * 32 + (l & 15);
        int l2 = l + 256;
        size_t o2 = (size_t)b * 1024 + (l2 >> 4) * 32 + (l2 & 15);
        hr[l]  = bf16_f(h2[o1]) + bf16_f(h2[o1 + 16]);
        hr[l2] = bf16_f(h2[o2]) + bf16_f(h2[o2 + 16]);
    }
    __syncthreads();
    float am = bm[l], as = bs[l];
    for (int k = 0; k < U; ++k) {
        float h = hr[k];
        am = fmaf(h, wm[(size_t)k * L + l], am);
        as = fmaf(h, wsig[(size_t)k * L + l], as);
    }
    lat[(size_t)b * L + l] = am + expf(as * 0.5f) * eps[(size_t)b * L + l];
}

// xcr[b][ugi*32+u*4+g] = dec_b0 + latent @ dec_Wx0[0:L]  (col oc = g*512+ugi*8+u)
__global__ void xcr_k(const float* __restrict__ lat, const float* __restrict__ Wx0,
                      const float* __restrict__ b0v, float* __restrict__ xcr)
{
    __shared__ float lr[L];
    int b = blockIdx.x >> 3;
    int oc = (blockIdx.x & 7) * 256 + threadIdx.x;
    lr[threadIdx.x] = lat[(size_t)b * L + threadIdx.x];
    __syncthreads();
    float acc = b0v[oc];
    for (int k = 0; k < L; ++k) acc = fmaf(lr[k], Wx0[(size_t)k * G4U + oc], acc);
    int g = oc >> 9, rest = oc & 511, ugi = rest >> 3, u = rest & 7;
    xcr[(size_t)b * G4U + ugi * 32 + u * 4 + g] = acc;
}

__global__ void biasref_k(const float* s0, const float* s1, const float* s2,
                          const float* s3, const float* s4, float* __restrict__ ebr)
{
    int idx = blockIdx.x * 256 + threadIdx.x;   // 5*2048
    int which = idx >> 11, oc = idx & 2047;
    const float* s = which == 0 ? s0 : which == 1 ? s1 : which == 2 ? s2
                   : which == 3 ? s3 : s4;
    int g = oc >> 9, rest = oc & 511, ugi = rest >> 3, u = rest & 7;
    ebr[which * 2048 + ugi * 32 + u * 4 + g] = s[oc];
}

// Wt[v][k] = dec_W[k][v]  (transposed projection weight, float4-loadable rows)
__global__ void wtprep_k(const float* __restrict__ W, float* __restrict__ Wt)
{
    int idx = blockIdx.x * 256 + threadIdx.x;   // 32768
    int k = idx >> 6, v = idx & 63;
    Wt[(size_t)v * 512 + k] = W[idx];
}

__global__ void barinit_k(int* __restrict__ bar)
{
    bar[blockIdx.x * 256 + threadIdx.x] = 0;   // 4096 ints (256 flag lines)
}

__global__ void sentinel_k(float* __restrict__ out, float val) { out[threadIdx.x] = val; }

extern "C" void kernel_launch(void* const* d_in, const int* in_sizes, int n_in,
                              void* d_out, int out_size, void* d_ws, size_t ws_size,
                              hipStream_t stream)
{
    const int*   tokens   = (const int*)  d_in[0];
    const float* eps      = (const float*)d_in[1];
    const float* emb      = (const float*)d_in[2];
    const float* enc_Wx0  = (const float*)d_in[3];
    const float* enc_Wh0  = (const float*)d_in[4];
    const float* enc_b0   = (const float*)d_in[5];
    const float* enc_Wx12 = (const float*)d_in[6];
    const float* enc_Wh12 = (const float*)d_in[7];
    const float* enc_b12  = (const float*)d_in[8];
    const float* w_mean   = (const float*)d_in[9];
    const float* b_mean   = (const float*)d_in[10];
    const float* w_sigma  = (const float*)d_in[11];
    const float* b_sigma  = (const float*)d_in[12];
    const float* dec_Wx0  = (const float*)d_in[13];
    const float* dec_Wh0  = (const float*)d_in[14];
    const float* dec_b0   = (const float*)d_in[15];
    const float* dec_Wx12 = (const float*)d_in[16];
    const float* dec_Wh12 = (const float*)d_in[17];
    const float* dec_b12  = (const float*)d_in[18];
    const float* dec_W    = (const float*)d_in[19];
    const float* dec_b    = (const float*)d_in[20];
    float* out = (float*)d_out;

    // workspace carve-up (all 16B aligned)
    unsigned short* xI  = (unsigned short*)d_ws;                  // B*T*128 us
    unsigned short* h   = xI + (size_t)B * T * 128;               // 6*HBUF us
    float* lat = (float*)(h + 6 * (size_t)HBUF);                  // B*L
    float* xcr = lat + (size_t)B * L;                             // B*2048
    float* ebr = xcr + (size_t)B * G4U;                           // 5*2048
    float* Wt  = ebr + 5 * G4U;                                   // 64*512
    int*   bar = (int*)(Wt + 64 * 512);                           // 4096 ints
    size_t need = (size_t)((char*)(bar + 4096) - (char*)d_ws);
    if (ws_size < need) {
        sentinel_k<<<dim3(1), dim3(64), 0, stream>>>(out, -1.0e6f);
        return;
    }

    const size_t UG = (size_t)U * G4U;

    embed_split_k<<<dim3(B * T * 16 / 256), dim3(256), 0, stream>>>(tokens, emb, xI);
    biasref_k<<<dim3(40), dim3(256), 0, stream>>>(enc_b0, enc_b12, enc_b12 + G4U,
                                                  dec_b12, dec_b12 + G4U, ebr);
    wtprep_k<<<dim3(128), dim3(256), 0, stream>>>(dec_W, Wt);

    auto coop = [&](int grid, const float* Wx0_, const float* Wh0_,
                    const float* Wx1_, const float* Wh1_,
                    const float* Wx2_, const float* Wh2_,
                    const float* cbb, const float* rb,
                    const float* pW, const float* pB, int np) -> hipError_t {
        const unsigned short* a_xI = xI;
        unsigned short* a_h = h;
        float* a_out = out;
        int* a_bar = bar;
        void* args[] = { (void*)&a_xI,
                         (void*)&Wx0_, (void*)&Wh0_, (void*)&Wx1_, (void*)&Wh1_,
                         (void*)&Wx2_, (void*)&Wh2_,
                         (void*)&cbb, (void*)&rb, (void*)&a_h,
                         (void*)&pW, (void*)&pB, (void*)&a_out, (void*)&np,
                         (void*)&a_bar };
        return hipLaunchCooperativeKernel((void*)vae_stack, dim3(grid), dim3(512),
                                          args, 0, stream);
    };

    // ---------------- encoder (192 blocks: no projection role) --------------
    barinit_k<<<dim3(16), dim3(256), 0, stream>>>(bar);
    hipError_t e1 = coop(192, enc_Wx0, enc_Wh0, enc_Wx12, enc_Wh12,
                         enc_Wx12 + UG, enc_Wh12 + UG,
                         ebr, nullptr, nullptr, nullptr, T + 2);

    // latent head reads encoder h2[t=255] (buf 1): interleaved panel 5
    latent_k<<<dim3(B), dim3(256), 0, stream>>>(h + 5 * (size_t)HBUF,
                                                eps, w_mean, b_mean, w_sigma, b_sigma, lat);
    xcr_k<<<dim3(2048), dim3(256), 0, stream>>>(lat, dec_Wx0, dec_b0, xcr);

    // ---------------- decoder (256 blocks, fused projection) ----------------
    barinit_k<<<dim3(16), dim3(256), 0, stream>>>(bar);
    hipError_t e2 = coop(256, dec_Wx0 + (size_t)L * G4U, dec_Wh0, dec_Wx12, dec_Wh12,
                         dec_Wx12 + UG, dec_Wh12 + UG,
                         ebr + 2 * G4U, xcr, Wt, dec_b, T + 3);

    if (e1 != hipSuccess || e2 != hipSuccess) {
        sentinel_k<<<dim3(1), dim3(64), 0, stream>>>(out, -3.0e6f);
    }
}

// Round 13
// 12122.150 us; speedup vs baseline: 1.8888x; 1.8204x over previous
//
#include <hip/hip_runtime.h>
#include <math.h>

#define B 256
#define T 256
#define U 512
#define L 256
#define V 64
#define G4U 2048
#define BU (B * U)
#define HBUF 262144   // ushorts per (layer,buf) h panel: 8 mtiles x 32 chunks x 1024

typedef __attribute__((ext_vector_type(8))) short bf16x8;
typedef __attribute__((ext_vector_type(16))) float f32x16;

__device__ __forceinline__ unsigned short bf16_hi(float x) {
    union { float f; unsigned int u; } c; c.f = x;
    unsigned int r = c.u + 0x7fffu + ((c.u >> 16) & 1u);   // RNE
    return (unsigned short)(r >> 16);
}
__device__ __forceinline__ float bf16_f(unsigned short h) {
    union { unsigned int u; float f; } c; c.u = ((unsigned int)h) << 16;
    return c.f;
}

// ---- MALL-coherent (sc0 sc1) access helpers -----------------------------
__device__ __forceinline__ void ld_coh16(const void* p, bf16x8& d) {
    asm volatile("global_load_dwordx4 %0, %1, off sc0 sc1"
                 : "=v"(d) : "v"(p));
}
__device__ __forceinline__ void ld_coh8(const void* p, unsigned long long& d) {
    asm volatile("global_load_dwordx2 %0, %1, off sc0 sc1"
                 : "=v"(d) : "v"(p));
}
__device__ __forceinline__ void st_coh32(void* p, unsigned int v) {
    asm volatile("global_store_dword %0, %1, off sc0 sc1"
                 :: "v"(p), "v"(v) : "memory");
}
__device__ __forceinline__ unsigned int ld_coh32_wait(const void* p) {
    unsigned int r;
    asm volatile("global_load_dword %0, %1, off sc0 sc1\n\t"
                 "s_waitcnt vmcnt(0)"
                 : "=v"(r) : "v"(p) : "memory");
    return r;
}
__device__ __forceinline__ void coh_drain() {
    asm volatile("s_waitcnt vmcnt(0)" ::: "memory");
    __builtin_amdgcn_sched_barrier(0);
}

// ---- point-to-point role-group flag sync (relaxed, coherent) ------------
__device__ __forceinline__ void flags_wait(int* bar, int wmask, int target, int lane)
{
    if (threadIdx.x < 64) {
        #pragma unroll
        for (int r = 0; r < 4; ++r) {
            if (wmask & (1 << r)) {
                const int fi = (r * 64 + lane) * 16;
                while ((int)ld_coh32_wait(&bar[fi]) < target)
                    __builtin_amdgcn_s_sleep(1);
            }
        }
    }
    __syncthreads();
}
__device__ __forceinline__ void flags_pub(int* bar, int bid, int val)
{
    asm volatile("s_waitcnt vmcnt(0)" ::: "memory");   // all stores MALL-acked
    __syncthreads();
    if (threadIdx.x == 0)
        st_coh32(&bar[bid * 16], (unsigned int)val);
}

// Simple 4-chunk GEMM (role0 x-part): xI read-only -> normal cached loads.
// xI keeps the per-row interleave [pos][chunk][16hi|16lo].
__device__ __forceinline__ void gemm4(const unsigned short* __restrict__ abase,
                                      const unsigned short* bhiB,
                                      const unsigned short* bloB,
                                      int kh8, f32x16& acc)
{
    bf16x8 ah[4], al[4];
    #pragma unroll
    for (int i = 0; i < 4; ++i) {
        ah[i] = *(const bf16x8*)(abase + i * 32 + kh8);
        al[i] = *(const bf16x8*)(abase + i * 32 + 16 + kh8);
    }
    #pragma unroll
    for (int i = 0; i < 4; ++i) {
        bf16x8 bh = *(const bf16x8*)(bhiB + i * 512);
        bf16x8 bl = *(const bf16x8*)(bloB + i * 512);
        acc = __builtin_amdgcn_mfma_f32_32x32x16_bf16(ah[i], bh, acc, 0, 0, 0);
        acc = __builtin_amdgcn_mfma_f32_32x32x16_bf16(ah[i], bl, acc, 0, 0, 0);
        acc = __builtin_amdgcn_mfma_f32_32x32x16_bf16(al[i], bh, acc, 0, 0, 0);
    }
}

// Pipelined GEMM over NCH chunks of a fragment-major coherent A panel.
// abase is pre-offset to this wave's mtile + lane fragment slot; each wave
// load covers ONE contiguous 1KB segment (16 sequential lines, 100% used).
template<int NCH>
__device__ __forceinline__ void gemm_sub_coh(const unsigned short* abase,
                                             const unsigned short* bhiB,
                                             const unsigned short* bloB,
                                             f32x16& acc)
{
    constexpr int NB = NCH / 8;
    bf16x8 ah[2][8], al[2][8];
    #pragma unroll
    for (int i = 0; i < 8; ++i) {
        ld_coh16(abase + i * 1024,       ah[0][i]);
        ld_coh16(abase + i * 1024 + 512, al[0][i]);
    }
    coh_drain();
    #pragma unroll
    for (int b = 0; b < NB; ++b) {
        const int cur = b & 1, nxt = cur ^ 1;
        if (b + 1 < NB) {
            #pragma unroll
            for (int i = 0; i < 8; ++i) {
                const int c = (b + 1) * 8 + i;
                ld_coh16(abase + c * 1024,       ah[nxt][i]);
                ld_coh16(abase + c * 1024 + 512, al[nxt][i]);
            }
        }
        #pragma unroll
        for (int i = 0; i < 8; ++i) {
            const int c = b * 8 + i;
            bf16x8 bh = *(const bf16x8*)(bhiB + c * 512);
            bf16x8 bl = *(const bf16x8*)(bloB + c * 512);
            acc = __builtin_amdgcn_mfma_f32_32x32x16_bf16(ah[cur][i], bh, acc, 0, 0, 0);
            acc = __builtin_amdgcn_mfma_f32_32x32x16_bf16(ah[cur][i], bl, acc, 0, 0, 0);
            acc = __builtin_amdgcn_mfma_f32_32x32x16_bf16(al[cur][i], bh, acc, 0, 0, 0);
        }
        coh_drain();
    }
}

// Fused 3-layer LSTM stack, diagonal-pipelined, split-bf16 MFMA.
// h panels FRAGMENT-MAJOR: [mtile][chunk][hi 32x16 | lo 32x16] ->
// A-loads are fully coalesced 1KB wave segments (R12 was 32 scattered
// half-used lines per load — the measured ~43µs/phase request-rate wall).
__global__ void __launch_bounds__(512, 1)
vae_stack(const unsigned short* __restrict__ xI,
          const float* __restrict__ Wx0, const float* __restrict__ Wh0,
          const float* __restrict__ Wx1, const float* __restrict__ Wh1,
          const float* __restrict__ Wx2, const float* __restrict__ Wh2,
          const float* __restrict__ cb_base, const float* __restrict__ rb0,
          unsigned short* __restrict__ h,
          const float* __restrict__ projW, const float* __restrict__ projB,
          float* __restrict__ out, int nphase, int* __restrict__ bar)
{
    __shared__ __align__(16) char smem[131072];
    const int nb = gridDim.x;
    const int tid = threadIdx.x;
    const int bid = blockIdx.x;
    const int role = bid >> 6;
    const int ug = bid & 63;
    const int lane = tid & 63;
    const int wv = tid >> 6;        // wave id = mtile
    const int m0 = wv * 32;

    // role dependence masks: {r-1 producer, r own-prev, r+1 WAR}
    const int allmask = (nb == 256) ? 0b1111 : 0b0111;
    int wmask;
    if      (role == 0) wmask = 0b0011;
    else if (role == 1) wmask = 0b0111;
    else if (role == 2) wmask = (nb == 256) ? 0b1110 : 0b0110;
    else                wmask = 0b0100;

    // zero all h buffers COHERENTLY
    {
        unsigned int* hz = (unsigned int*)h;
        const int stride = nb * 512;
        for (int i = bid * 512 + tid; i < 786432; i += stride)
            st_coh32(hz + i, 0u);
    }

    auto HP = [&](int layer, int buf) -> unsigned short* {
        return h + (size_t)(layer * 2 + buf) * HBUF;
    };

    if (role < 3) {
        const int K  = (role == 0) ? 576 : 1024;
        const int Dx = (role == 0) ? 64 : 512;
        unsigned short* Whi = (unsigned short*)smem;             // lower 64KB
        unsigned short* Wlo = (unsigned short*)(smem + 65536);   // upper 64KB

        // one-time weight stage, both planes (col slot n = u*4+g; col = g*512+ug*8+u)
        const float* WxL = (role == 0) ? Wx0 : ((role == 1) ? Wx1 : Wx2);
        const float* WhL = (role == 0) ? Wh0 : ((role == 1) ? Wh1 : Wh2);
        for (int idx = tid; idx < K * 32; idx += 512) {
            int k = idx >> 5, n = idx & 31, u = n >> 2, g = n & 3;
            int col = g * 512 + ug * 8 + u;
            float w = (k < Dx) ? WxL[(size_t)k * G4U + col]
                               : WhL[(size_t)(k - Dx) * G4U + col];
            unsigned short hi = bf16_hi(w);
            int off = ((k >> 3) * 32 + n) * 8 + (k & 7);
            Whi[off] = hi;
            Wlo[off] = bf16_hi(w - bf16_f(hi));
        }

        const bool userb = (role == 0) && (rb0 != nullptr);
        const float colbias = userb ? 0.0f
                            : cb_base[role * 2048 + ug * 32 + (lane & 31)];
        float cst[16];
        #pragma unroll
        for (int i = 0; i < 16; ++i) cst[i] = 0.0f;

        const int arow = m0 + (lane & 31);      // A row (batch) — for xI only
        const int kh8  = (lane >> 5) * 8;       // k-half offset (xI layout)
        const int frg  = (lane >> 5) * 256 + (lane & 31) * 8;  // B frag offset
        // fragment-major A slot for this lane (within a (mtile,chunk) block)
        const int lf   = (lane & 31) * 16 + (lane >> 5) * 8;
        const size_t mt = (size_t)wv * 32768;   // mtile base (ushorts)

        // init rendezvous
        flags_pub(bar, bid, 1);
        flags_wait(bar, allmask, 1, lane);

        for (int p = 0; p < nphase; ++p) {
            flags_wait(bar, wmask, p + 1, lane);   // deps finished phase p-1
            const int t = p - role;
            if (t >= 0 && t < T) {
                const int wr = t & 1, rd = wr ^ 1;
                f32x16 acc;
                #pragma unroll
                for (int i = 0; i < 16; ++i) acc[i] = 0.0f;

                if (role == 0) {
                    gemm4(xI + ((size_t)arow * T + t) * 128,
                          Whi + frg, Wlo + frg, kh8, acc);
                    gemm_sub_coh<32>(HP(0, rd) + mt + lf,
                                     Whi + 4 * 512 + frg, Wlo + 4 * 512 + frg, acc);
                } else {
                    gemm_sub_coh<32>(HP(role - 1, wr) + mt + lf,
                                     Whi + frg, Wlo + frg, acc);
                    gemm_sub_coh<32>(HP(role, rd) + mt + lf,
                                     Whi + 32 * 512 + frg, Wlo + 32 * 512 + frg, acc);
                }

                // pointwise: C layout col=lane&31, row=(r&3)+8*(r>>2)+4*(lane>>5)
                const int n = lane & 31, g = n & 3, u8 = n >> 2, hi5 = lane >> 5;
                unsigned short* hw = HP(role, wr);
                const int gu = ug * 8 + u8;
                const int cg = gu >> 4, eg = gu & 15;   // chunk / elem in frag block
                const bool g1 = (g & 1), g2 = (g & 2);
                const bool store_t = (g == 0) && !(u8 & 1);   // u32 pair stores
                #pragma unroll
                for (int r = 0; r < 16; ++r) {
                    int ri = (r & 3) + 8 * (r >> 2) + 4 * hi5;   // row in mtile
                    float z = acc[r] + colbias;
                    if (userb) z += rb0[(size_t)(m0 + ri) * G4U + ug * 32 + n];
                    float zb = __shfl_xor(z, 1, 64);
                    float zc = __shfl_xor(z, 2, 64);
                    float zd = __shfl_xor(z, 3, 64);
                    float t01 = g1 ? zb : z,  t23 = g1 ? zd : zc;
                    float u01 = g1 ? z  : zb, u23 = g1 ? zc : zd;
                    float zi = g2 ? t23 : t01;
                    float zf = g2 ? u23 : u01;
                    float zG = g2 ? t01 : t23;
                    float zo = g2 ? u01 : u23;
                    float ig = 1.0f / (1.0f + expf(-zi));
                    float fg = 1.0f / (1.0f + expf(-zf));
                    float gg = tanhf(zG);
                    float og = 1.0f / (1.0f + expf(-zo));
                    cst[r] = fg * cst[r] + ig * gg;
                    float hv = og * tanhf(cst[r]);
                    unsigned short hh2 = bf16_hi(hv);
                    unsigned short hl2 = bf16_hi(hv - bf16_f(hh2));
                    // pair with partner unit (u8^1) via lane^4
                    unsigned int hh_p = (unsigned int)__shfl_xor((int)hh2, 4, 64);
                    unsigned int hl_p = (unsigned int)__shfl_xor((int)hl2, 4, 64);
                    if (store_t) {
                        size_t ho = mt + (size_t)cg * 1024 + ri * 16 + eg;
                        st_coh32(hw + ho,       (unsigned int)hh2 | (hh_p << 16));
                        st_coh32(hw + ho + 512, (unsigned int)hl2 | (hl_p << 16));
                    }
                }
            }
            flags_pub(bar, bid, p + 2);
        }
    } else {
        // ---------------- projection + argmax (decoder only) ----------------
        float* hrow  = (float*)smem;            // [4][512]
        float* parts = (float*)(smem + 8192);   // [256]
        const int b0p = ug * 4;
        const float pbv = projW ? projB[lane] : 0.0f;
        const int r = wv & 3, kp = wv >> 2, v = lane;
        flags_pub(bar, bid, 1);
        flags_wait(bar, allmask, 1, lane);
        for (int p = 0; p < nphase; ++p) {
            flags_wait(bar, wmask, p + 1, lane);
            const int tp = p - 3;
            if (projW && tp >= 0 && tp < T) {
                {   // stage 4 h2 rows (hi+lo recon) into LDS — coherent reads
                    int rr = tid >> 7, kq = (tid & 127) * 4;
                    int grow = b0p + rr;
                    int c = kq >> 4, e = kq & 15;
                    const unsigned short* hb2 = HP(2, tp & 1)
                        + (size_t)(grow >> 5) * 32768 + (size_t)c * 1024
                        + (grow & 31) * 16 + e;
                    unsigned long long uh, ul;
                    ld_coh8(hb2, uh);
                    ld_coh8(hb2 + 512, ul);
                    coh_drain();
                    float4 f;
                    f.x = bf16_f((unsigned short)(uh))       + bf16_f((unsigned short)(ul));
                    f.y = bf16_f((unsigned short)(uh >> 16)) + bf16_f((unsigned short)(ul >> 16));
                    f.z = bf16_f((unsigned short)(uh >> 32)) + bf16_f((unsigned short)(ul >> 32));
                    f.w = bf16_f((unsigned short)(uh >> 48)) + bf16_f((unsigned short)(ul >> 48));
                    *(float4*)(hrow + rr * 512 + kq) = f;
                }
                __syncthreads();
                float acc = 0.0f;
                const float* wp = projW + (size_t)v * 512 + kp * 256;
                const float* hp = hrow + r * 512 + kp * 256;
                #pragma unroll 8
                for (int q = 0; q < 64; ++q) {
                    float4 w  = *(const float4*)(wp + q * 4);
                    float4 hq = *(const float4*)(hp + q * 4);
                    acc = fmaf(w.x, hq.x, acc); acc = fmaf(w.y, hq.y, acc);
                    acc = fmaf(w.z, hq.z, acc); acc = fmaf(w.w, hq.w, acc);
                }
                if (kp == 1) parts[r * 64 + v] = acc;
                __syncthreads();
                if (kp == 0) {
                    float logit = acc + parts[r * 64 + v] + pbv;
                    int grow = b0p + r;
                    __builtin_nontemporal_store(
                        logit, &out[(size_t)B * T + ((size_t)grow * T + tp) * V + v]);
                    float best = logit; int bi = v;
                    #pragma unroll
                    for (int off = 32; off; off >>= 1) {
                        float ov = __shfl_xor(best, off, 64);
                        int oi  = __shfl_xor(bi, off, 64);
                        if (ov > best || (ov == best && oi < bi)) { best = ov; bi = oi; }
                    }
                    if (v == 0)
                        __builtin_nontemporal_store((float)bi,
                                                    &out[(size_t)grow * T + tp]);
                }
            }
            flags_pub(bar, bid, p + 2);
        }
    }
}

// ---------------- prep kernels ----------------
// x interleaved: xI[pos*128 + c*32 + kk] = hi(emb[k=c*16+kk]), +16 = lo
__global__ void embed_split_k(const int* __restrict__ tok, const float* __restrict__ emb,
                              unsigned short* __restrict__ xI)
{
    int idx = blockIdx.x * 256 + threadIdx.x;   // B*T*16 quads
    int pos = idx >> 4, q = idx & 15;
    int c = q >> 2, kk4 = (q & 3) * 4;
    int tk = tok[pos];
    float4 v = *(const float4*)(emb + (size_t)tk * V + q * 4);
    ushort4 hh, ll;
    hh.x = bf16_hi(v.x); ll.x = bf16_hi(v.x - bf16_f(hh.x));
    hh.y = bf16_hi(v.y); ll.y = bf16_hi(v.y - bf16_f(hh.y));
    hh.z = bf16_hi(v.z); ll.z = bf16_hi(v.z - bf16_f(hh.z));
    hh.w = bf16_hi(v.w); ll.w = bf16_hi(v.w - bf16_f(hh.w));
    size_t base = (size_t)pos * 128 + c * 32 + kk4;
    *(ushort4*)(xI + base) = hh;
    *(ushort4*)(xI + base + 16) = ll;
}

// latent head: h2 panel is fragment-major
__global__ void latent_k(const unsigned short* __restrict__ h2,
                         const float* __restrict__ eps,
                         const float* __restrict__ wm, const float* __restrict__ bm,
                         const float* __restrict__ wsig, const float* __restrict__ bs,
                         float* __restrict__ lat)
{
    __shared__ float hr[U];
    int b = blockIdx.x, l = threadIdx.x;
    {
        size_t o1 = (size_t)(b >> 5) * 32768 + (size_t)(l >> 4) * 1024
                  + (b & 31) * 16 + (l & 15);
        int l2 = l + 256;
        size_t o2 = (size_t)(b >> 5) * 32768 + (size_t)(l2 >> 4) * 1024
                  + (b & 31) * 16 + (l2 & 15);
        hr[l]  = bf16_f(h2[o1]) + bf16_f(h2[o1 + 512]);
        hr[l2] = bf16_f(h2[o2]) + bf16_f(h2[o2 + 512]);
    }
    __syncthreads();
    float am = bm[l], as = bs[l];
    for (int k = 0; k < U; ++k) {
        float h = hr[k];
        am = fmaf(h, wm[(size_t)k * L + l], am);
        as = fmaf(h, wsig[(size_t)k * L + l], as);
    }
    lat[(size_t)b * L + l] = am + expf(as * 0.5f) * eps[(size_t)b * L + l];
}

// xcr[b][ugi*32+u*4+g] = dec_b0 + latent @ dec_Wx0[0:L]  (col oc = g*512+ugi*8+u)
__global__ void xcr_k(const float* __restrict__ lat, const float* __restrict__ Wx0,
                      const float* __restrict__ b0v, float* __restrict__ xcr)
{
    __shared__ float lr[L];
    int b = blockIdx.x >> 3;
    int oc = (blockIdx.x & 7) * 256 + threadIdx.x;
    lr[threadIdx.x] = lat[(size_t)b * L + threadIdx.x];
    __syncthreads();
    float acc = b0v[oc];
    for (int k = 0; k < L; ++k) acc = fmaf(lr[k], Wx0[(size_t)k * G4U + oc], acc);
    int g = oc >> 9, rest = oc & 511, ugi = rest >> 3, u = rest & 7;
    xcr[(size_t)b * G4U + ugi * 32 + u * 4 + g] = acc;
}

__global__ void biasref_k(const float* s0, const float* s1, const float* s2,
                          const float* s3, const float* s4, float* __restrict__ ebr)
{
    int idx = blockIdx.x * 256 + threadIdx.x;   // 5*2048
    int which = idx >> 11, oc = idx & 2047;
    const float* s = which == 0 ? s0 : which == 1 ? s1 : which == 2 ? s2
                   : which == 3 ? s3 : s4;
    int g = oc >> 9, rest = oc & 511, ugi = rest >> 3, u = rest & 7;
    ebr[which * 2048 + ugi * 32 + u * 4 + g] = s[oc];
}

// Wt[v][k] = dec_W[k][v]
__global__ void wtprep_k(const float* __restrict__ W, float* __restrict__ Wt)
{
    int idx = blockIdx.x * 256 + threadIdx.x;   // 32768
    int k = idx >> 6, v = idx & 63;
    Wt[(size_t)v * 512 + k] = W[idx];
}

__global__ void barinit_k(int* __restrict__ bar)
{
    bar[blockIdx.x * 256 + threadIdx.x] = 0;   // 4096 ints
}

__global__ void sentinel_k(float* __restrict__ out, float val) { out[threadIdx.x] = val; }

extern "C" void kernel_launch(void* const* d_in, const int* in_sizes, int n_in,
                              void* d_out, int out_size, void* d_ws, size_t ws_size,
                              hipStream_t stream)
{
    const int*   tokens   = (const int*)  d_in[0];
    const float* eps      = (const float*)d_in[1];
    const float* emb      = (const float*)d_in[2];
    const float* enc_Wx0  = (const float*)d_in[3];
    const float* enc_Wh0  = (const float*)d_in[4];
    const float* enc_b0   = (const float*)d_in[5];
    const float* enc_Wx12 = (const float*)d_in[6];
    const float* enc_Wh12 = (const float*)d_in[7];
    const float* enc_b12  = (const float*)d_in[8];
    const float* w_mean   = (const float*)d_in[9];
    const float* b_mean   = (const float*)d_in[10];
    const float* w_sigma  = (const float*)d_in[11];
    const float* b_sigma  = (const float*)d_in[12];
    const float* dec_Wx0  = (const float*)d_in[13];
    const float* dec_Wh0  = (const float*)d_in[14];
    const float* dec_b0   = (const float*)d_in[15];
    const float* dec_Wx12 = (const float*)d_in[16];
    const float* dec_Wh12 = (const float*)d_in[17];
    const float* dec_b12  = (const float*)d_in[18];
    const float* dec_W    = (const float*)d_in[19];
    const float* dec_b    = (const float*)d_in[20];
    float* out = (float*)d_out;

    // workspace carve-up (all 16B aligned)
    unsigned short* xI  = (unsigned short*)d_ws;                  // B*T*128 us
    unsigned short* h   = xI + (size_t)B * T * 128;               // 6*HBUF us
    float* lat = (float*)(h + 6 * (size_t)HBUF);                  // B*L
    float* xcr = lat + (size_t)B * L;                             // B*2048
    float* ebr = xcr + (size_t)B * G4U;                           // 5*2048
    float* Wt  = ebr + 5 * G4U;                                   // 64*512
    int*   bar = (int*)(Wt + 64 * 512);                           // 4096 ints
    size_t need = (size_t)((char*)(bar + 4096) - (char*)d_ws);
    if (ws_size < need) {
        sentinel_k<<<dim3(1), dim3(64), 0, stream>>>(out, -1.0e6f);
        return;
    }

    const size_t UG = (size_t)U * G4U;

    embed_split_k<<<dim3(B * T * 16 / 256), dim3(256), 0, stream>>>(tokens, emb, xI);
    biasref_k<<<dim3(40), dim3(256), 0, stream>>>(enc_b0, enc_b12, enc_b12 + G4U,
                                                  dec_b12, dec_b12 + G4U, ebr);
    wtprep_k<<<dim3(128), dim3(256), 0, stream>>>(dec_W, Wt);

    auto coop = [&](int grid, const float* Wx0_, const float* Wh0_,
                    const float* Wx1_, const float* Wh1_,
                    const float* Wx2_, const float* Wh2_,
                    const float* cbb, const float* rb,
                    const float* pW, const float* pB, int np) -> hipError_t {
        const unsigned short* a_xI = xI;
        unsigned short* a_h = h;
        float* a_out = out;
        int* a_bar = bar;
        void* args[] = { (void*)&a_xI,
                         (void*)&Wx0_, (void*)&Wh0_, (void*)&Wx1_, (void*)&Wh1_,
                         (void*)&Wx2_, (void*)&Wh2_,
                         (void*)&cbb, (void*)&rb, (void*)&a_h,
                         (void*)&pW, (void*)&pB, (void*)&a_out, (void*)&np,
                         (void*)&a_bar };
        return hipLaunchCooperativeKernel((void*)vae_stack, dim3(grid), dim3(512),
                                          args, 0, stream);
    };

    // ---------------- encoder (192 blocks: no projection role) --------------
    barinit_k<<<dim3(16), dim3(256), 0, stream>>>(bar);
    hipError_t e1 = coop(192, enc_Wx0, enc_Wh0, enc_Wx12, enc_Wh12,
                         enc_Wx12 + UG, enc_Wh12 + UG,
                         ebr, nullptr, nullptr, nullptr, T + 2);

    // latent head reads encoder h2[t=255] (buf 1): panel 5
    latent_k<<<dim3(B), dim3(256), 0, stream>>>(h + 5 * (size_t)HBUF,
                                                eps, w_mean, b_mean, w_sigma, b_sigma, lat);
    xcr_k<<<dim3(2048), dim3(256), 0, stream>>>(lat, dec_Wx0, dec_b0, xcr);

    // ---------------- decoder (256 blocks, fused projection) ----------------
    barinit_k<<<dim3(16), dim3(256), 0, stream>>>(bar);
    hipError_t e2 = coop(256, dec_Wx0 + (size_t)L * G4U, dec_Wh0, dec_Wx12, dec_Wh12,
                         dec_Wx12 + UG, dec_Wh12 + UG,
                         ebr + 2 * G4U, xcr, Wt, dec_b, T + 3);

    if (e1 != hipSuccess || e2 != hipSuccess) {
        sentinel_k<<<dim3(1), dim3(64), 0, stream>>>(out, -3.0e6f);
    }
}